// Round 2
// baseline (1525.603 us; speedup 1.0000x reference)
//
#include <hip/hip_runtime.h>
#include <hip/hip_bf16.h>

// Problem constants
constexpr int BATCH = 8;
constexpr int SEQ   = 1024;
constexpr int CH    = 1536;
constexpr int NH    = 12;
constexpr int HD    = 128;       // head dim
constexpr int FFDIM = 6144;      // 4*CH
constexpr int NROWS = BATCH * SEQ;   // 8192
constexpr int QKVLD = 3 * CH;    // 4608, fused QKV row stride
constexpr float EPS = 1e-5f;

typedef unsigned short ushort;
typedef __attribute__((ext_vector_type(8))) ushort us8;
typedef __attribute__((ext_vector_type(8))) __bf16 bf16x8;
typedef __attribute__((ext_vector_type(4))) float f32x4;

__device__ __forceinline__ float b2f(ushort u) {
  return __uint_as_float(((unsigned)u) << 16);
}
__device__ __forceinline__ ushort f2b(float f) {
  __hip_bfloat16 h = __float2bfloat16(f);  // RNE
  return *reinterpret_cast<ushort*>(&h);
}

// async global->LDS, 16 bytes per lane. LDS dest = wave-uniform base + lane*16.
__device__ __forceinline__ void g2l16(const ushort* g, ushort* l) {
  __builtin_amdgcn_global_load_lds(
      (const __attribute__((address_space(1))) void*)g,
      (__attribute__((address_space(3))) void*)l, 16, 0, 0);
}

// ---------------- block reduction helper (blockDim == 256) ----------------
__device__ __forceinline__ float block_sum(float v, float* red) {
#pragma unroll
  for (int o = 32; o > 0; o >>= 1) v += __shfl_down(v, o, 64);
  const int w = threadIdx.x >> 6;
  if ((threadIdx.x & 63) == 0) red[w] = v;
  __syncthreads();
  const float r = red[0] + red[1] + red[2] + red[3];
  __syncthreads();
  return r;
}

// ---------------- LayerNorm over last dim (CH), bf16 output ----------------
__global__ __launch_bounds__(256) void ln_bf16(const float* __restrict__ x,
                                               const float* __restrict__ g,
                                               const float* __restrict__ b,
                                               ushort* __restrict__ out) {
  __shared__ float row[CH];
  __shared__ float red[4];
  const size_t base = (size_t)blockIdx.x * CH;
  float s = 0.f;
  for (int c = threadIdx.x; c < CH; c += 256) {
    const float v = x[base + c];
    row[c] = v;
    s += v;
  }
  const float mean = block_sum(s, red) * (1.0f / CH);
  float s2 = 0.f;
  for (int c = threadIdx.x; c < CH; c += 256) {
    const float d = row[c] - mean;
    s2 += d * d;
  }
  const float var = block_sum(s2, red) * (1.0f / CH);
  const float rstd = rsqrtf(var + EPS);
  for (int c = threadIdx.x; c < CH; c += 256)
    out[base + c] = f2b((row[c] - mean) * rstd * g[c] + b[c]);
}

// ---------------- transpose + fp32->bf16 cast for weights ----------------
__global__ __launch_bounds__(256) void transpose_cast(const float* __restrict__ src,
                                                      ushort* __restrict__ dst,
                                                      int R, int Cc, int ldd,
                                                      long srcZ, long dstZ) {
  __shared__ float tile[32][33];
  src += (size_t)blockIdx.z * srcZ;
  dst += (size_t)blockIdx.z * dstZ;
  const int c0 = blockIdx.x * 32, r0 = blockIdx.y * 32;
  const int tx = threadIdx.x & 31, ty = threadIdx.x >> 5;  // 32 x 8
#pragma unroll
  for (int i = ty; i < 32; i += 8)
    tile[i][tx] = src[(size_t)(r0 + i) * Cc + c0 + tx];
  __syncthreads();
#pragma unroll
  for (int i = ty; i < 32; i += 8)
    dst[(size_t)(c0 + i) * ldd + r0 + tx] = f2b(tile[tx][i]);
}

// ---------------- bf16 V transpose: (b,t,h,d) -> (b,h,d,t) ----------------
__global__ __launch_bounds__(256) void transpose_v(const ushort* __restrict__ src,
                                                   ushort* __restrict__ dst) {
  __shared__ ushort tile[32][33];
  const int bh = blockIdx.z;
  const int b = bh / NH, h = bh % NH;
  const ushort* s = src + (size_t)b * SEQ * QKVLD + (size_t)h * HD;
  ushort* d = dst + (size_t)bh * HD * SEQ;
  const int t0 = blockIdx.x * 32, d0 = blockIdx.y * 32;
  const int tx = threadIdx.x & 31, ty = threadIdx.x >> 5;  // 32 x 8
#pragma unroll
  for (int i = ty; i < 32; i += 8)
    tile[i][tx] = s[(size_t)(t0 + i) * QKVLD + d0 + tx];   // tile[t][d]
  __syncthreads();
#pragma unroll
  for (int i = ty; i < 32; i += 8)
    d[(size_t)(d0 + i) * SEQ + t0 + tx] = tile[tx][i];     // dst[d][t]
}

// ---------------- bf16 MFMA GEMM (m97-style: global_load_lds staging) ------
// C[m,n] = sum_k A[m,k] * Bt[n,k]  (+bias[n]) (relu) (+res[m,n])
constexpr int BT = 128;   // tile M and N
constexpr int BK = 32;    // K tile (bf16)

template <int RELU, int BIAS, int RES, int OUTBF>
__global__ __launch_bounds__(256) void gemm_bf16(
    const ushort* __restrict__ A, int lda,
    const ushort* __restrict__ Bt, int ldb,
    void* __restrict__ Cm, int ldc,
    const float* __restrict__ bias,
    const float* __restrict__ res, int ldr,
    int K) {
  __shared__ ushort As[BT * BK];  // 8 KB
  __shared__ ushort Bs[BT * BK];  // 8 KB
  const int tid = threadIdx.x;
  const int lane = tid & 63;
  const int wv = tid >> 6;
  const int m0 = blockIdx.y * BT;
  const int n0 = blockIdx.x * BT;
  const int srow = wv * 32 + (lane >> 2);
  const int schunk = (lane & 3) * 8;
  const ushort* gA0 = A + (size_t)(m0 + srow) * lda + schunk;
  const ushort* gA1 = gA0 + (size_t)16 * lda;
  const ushort* gB0 = Bt + (size_t)(n0 + srow) * ldb + schunk;
  const ushort* gB1 = gB0 + (size_t)16 * ldb;
  ushort* lA0 = As + (wv * 32) * BK;
  ushort* lA1 = lA0 + 16 * BK;
  ushort* lB0 = Bs + (wv * 32) * BK;
  ushort* lB1 = lB0 + 16 * BK;
  const int wm = (wv >> 1) * 64, wn = (wv & 1) * 64;
  const int fr = lane & 15;
  const int quad = lane >> 4;
  const int koff = quad * 8;

  f32x4 acc[4][4] = {{}};
  for (int k0 = 0; k0 < K; k0 += BK) {
    __syncthreads();
    g2l16(gA0 + k0, lA0);
    g2l16(gA1 + k0, lA1);
    g2l16(gB0 + k0, lB0);
    g2l16(gB1 + k0, lB1);
    __syncthreads();
    bf16x8 af[4], bf[4];
#pragma unroll
    for (int mi = 0; mi < 4; ++mi)
      af[mi] = *(const bf16x8*)&As[(wm + mi * 16 + fr) * BK + koff];
#pragma unroll
    for (int ni = 0; ni < 4; ++ni)
      bf[ni] = *(const bf16x8*)&Bs[(wn + ni * 16 + fr) * BK + koff];
#pragma unroll
    for (int mi = 0; mi < 4; ++mi)
#pragma unroll
      for (int ni = 0; ni < 4; ++ni)
        acc[mi][ni] = __builtin_amdgcn_mfma_f32_16x16x32_bf16(af[mi], bf[ni], acc[mi][ni], 0, 0, 0);
  }
#pragma unroll
  for (int ni = 0; ni < 4; ++ni) {
    const int col = n0 + wn + ni * 16 + fr;
    const float bs = BIAS ? bias[col] : 0.f;
#pragma unroll
    for (int mi = 0; mi < 4; ++mi) {
      const int rowb = m0 + wm + mi * 16 + quad * 4;
#pragma unroll
      for (int r = 0; r < 4; ++r) {
        float v = acc[mi][ni][r] + bs;
        if (RELU) v = fmaxf(v, 0.f);
        const size_t idx = (size_t)(rowb + r) * ldc + col;
        if (RES) v += res[(size_t)(rowb + r) * ldr + col];
        if (OUTBF) ((ushort*)Cm)[idx] = f2b(v);
        else       ((float*)Cm)[idx] = v;
      }
    }
  }
}

// ---------------- MFMA flash attention, barrier-free inner loop ------------
// V is pre-transposed in global (vt[b][h][d][t]); PV loads B-fragments
// directly from global like the QK^T step does for K. Ps is per-wave, so
// no __syncthreads anywhere in the K/V loop -> waves run independently.
constexpr int FQT = 64;   // queries per block
constexpr int VLD = 72;   // LDS row stride (ushorts)

__global__ __launch_bounds__(256) void flash_attn_mfma(
    const ushort* __restrict__ q, const ushort* __restrict__ k,
    const ushort* __restrict__ vt, ushort* __restrict__ o,
    int ld, int ldo) {
  __shared__ ushort Ps[4][16][VLD];  // per-wave P tiles (9 KB total)
  const int tid = threadIdx.x;
  const int lane = tid & 63;
  const int w = tid >> 6;
  const int fr = lane & 15;
  const int quad = lane >> 4;
  const int qt = blockIdx.x;
  const int b = blockIdx.y / NH;
  const int h = blockIdx.y % NH;
  const size_t base = (size_t)b * SEQ * ld + (size_t)h * HD;
  const ushort* vtb = vt + (size_t)(b * NH + h) * HD * SEQ;
  const int q0 = qt * FQT;
  const int qrow = q0 + w * 16;
  const float scale = 0.08838834764831845f;  // 1/sqrt(128)

  bf16x8 aq[4];
  {
    const ushort* qp = q + base + (size_t)(qrow + fr) * ld + quad * 8;
#pragma unroll
    for (int ks = 0; ks < 4; ++ks) aq[ks] = *(const bf16x8*)(qp + ks * 32);
  }

  float m_i[4], l_i[4];
  f32x4 oacc[8];
#pragma unroll
  for (int i = 0; i < 4; ++i) { m_i[i] = -3.0e38f; l_i[i] = 0.f; }
#pragma unroll
  for (int n8 = 0; n8 < 8; ++n8) oacc[n8] = (f32x4){0.f, 0.f, 0.f, 0.f};

  for (int jt = 0; jt <= qt; ++jt) {
    const int j0 = jt * FQT;
    f32x4 sacc[4];
#pragma unroll
    for (int ni = 0; ni < 4; ++ni) sacc[ni] = (f32x4){0.f, 0.f, 0.f, 0.f};
#pragma unroll
    for (int ks = 0; ks < 4; ++ks) {
      const ushort* kp = k + base + (size_t)(j0 + fr) * ld + ks * 32 + quad * 8;
#pragma unroll
      for (int ni = 0; ni < 4; ++ni) {
        const bf16x8 kf = *(const bf16x8*)(kp + (size_t)(ni * 16) * ld);
        sacc[ni] = __builtin_amdgcn_mfma_f32_16x16x32_bf16(aq[ks], kf, sacc[ni], 0, 0, 0);
      }
    }
    const bool diag = (jt == qt);
    float alpha[4];
#pragma unroll
    for (int i = 0; i < 4; ++i) {
      const int qg = qrow + quad * 4 + i;
      float pv[4];
      float vmax = -3.0e38f;
#pragma unroll
      for (int ni = 0; ni < 4; ++ni) {
        float sv = sacc[ni][i] * scale;
        if (diag && (j0 + ni * 16 + fr > qg)) sv = -3.0e38f;
        pv[ni] = sv;
        vmax = fmaxf(vmax, sv);
      }
#pragma unroll
      for (int mm = 8; mm >= 1; mm >>= 1) vmax = fmaxf(vmax, __shfl_xor(vmax, mm, 64));
      const float m_new = fmaxf(m_i[i], vmax);
      alpha[i] = __expf(m_i[i] - m_new);
      m_i[i] = m_new;
      float rsum = 0.f;
#pragma unroll
      for (int ni = 0; ni < 4; ++ni) {
        const float pe = __expf(pv[ni] - m_new);
        Ps[w][quad * 4 + i][ni * 16 + fr] = f2b(pe);
        rsum += pe;
      }
#pragma unroll
      for (int mm = 8; mm >= 1; mm >>= 1) rsum += __shfl_xor(rsum, mm, 64);
      l_i[i] = l_i[i] * alpha[i] + rsum;
#pragma unroll
      for (int n8 = 0; n8 < 8; ++n8) oacc[n8][i] *= alpha[i];
    }
    // PV: B-fragments straight from global V^T rows (d = n8*16+fr)
#pragma unroll
    for (int js = 0; js < 2; ++js) {
      const bf16x8 pf = *(const bf16x8*)&Ps[w][fr][js * 32 + quad * 8];
      const ushort* vp = vtb + (size_t)fr * SEQ + j0 + js * 32 + quad * 8;
#pragma unroll
      for (int n8 = 0; n8 < 8; ++n8) {
        const bf16x8 vf = *(const bf16x8*)(vp + (size_t)(n8 * 16) * SEQ);
        oacc[n8] = __builtin_amdgcn_mfma_f32_16x16x32_bf16(pf, vf, oacc[n8], 0, 0, 0);
      }
    }
  }
#pragma unroll
  for (int i = 0; i < 4; ++i) {
    const float inv = 1.0f / l_i[i];
    ushort* op = o + ((size_t)b * SEQ + qrow + quad * 4 + i) * ldo + (size_t)h * HD;
#pragma unroll
    for (int n8 = 0; n8 < 8; ++n8) op[n8 * 16 + fr] = f2b(oacc[n8][i] * inv);
  }
}

// ---------------- BatchNorm over (B, C) per T channel (fp32) ----------------
__global__ __launch_bounds__(256) void bn_stats(const float* __restrict__ x,
                                                float* __restrict__ mean,
                                                float* __restrict__ rstd) {
  __shared__ float red[4];
  const int t = blockIdx.x;
  float s = 0.f;
  for (int bb = 0; bb < BATCH; ++bb) {
    const float* p = x + ((size_t)bb * SEQ + t) * CH;
    for (int c = threadIdx.x; c < CH; c += 256) s += p[c];
  }
  const float m = block_sum(s, red) * (1.0f / (BATCH * CH));
  float s2 = 0.f;
  for (int bb = 0; bb < BATCH; ++bb) {
    const float* p = x + ((size_t)bb * SEQ + t) * CH;
    for (int c = threadIdx.x; c < CH; c += 256) {
      const float d = p[c] - m;
      s2 += d * d;
    }
  }
  const float var = block_sum(s2, red) * (1.0f / (BATCH * CH));
  if (threadIdx.x == 0) {
    mean[t] = m;
    rstd[t] = rsqrtf(var + EPS);
  }
}

__global__ __launch_bounds__(256) void bn_apply(const float* __restrict__ x,
                                                float* __restrict__ out,
                                                const float* __restrict__ mean,
                                                const float* __restrict__ rstd,
                                                const float* __restrict__ g,
                                                const float* __restrict__ bb) {
  const size_t i = (size_t)blockIdx.x * 256 + threadIdx.x;
  const int t = (int)((i / CH) % SEQ);
  out[i] = (x[i] - mean[t]) * rstd[t] * g[t] + bb[t];
}

// ---------------- launch ----------------
extern "C" void kernel_launch(void* const* d_in, const int* in_sizes, int n_in,
                              void* d_out, int out_size, void* d_ws, size_t ws_size,
                              hipStream_t stream) {
  const float* x    = (const float*)d_in[0];
  const float* wq   = (const float*)d_in[1];
  const float* wk   = (const float*)d_in[2];
  const float* wv   = (const float*)d_in[3];
  const float* wo   = (const float*)d_in[4];
  const float* bo   = (const float*)d_in[5];
  const float* ln1g = (const float*)d_in[6];
  const float* ln1b = (const float*)d_in[7];
  const float* ln2g = (const float*)d_in[8];
  const float* ln2b = (const float*)d_in[9];
  const float* w1   = (const float*)d_in[10];
  const float* b1   = (const float*)d_in[11];
  const float* w2   = (const float*)d_in[12];
  const float* b2   = (const float*)d_in[13];
  const float* bn1g = (const float*)d_in[14];
  const float* bn1b = (const float*)d_in[15];
  const float* bn2g = (const float*)d_in[16];
  const float* bn2b = (const float*)d_in[17];
  float* out = (float*)d_out;   // X1 fp32 residual stream lives here

  // Workspace (ushort units). Peak ~119.6 MB (unchanged: VT reuses R0,
  // attention output reuses the Q slot of QKV).
  ushort* wsu = (ushort*)d_ws;
  const size_t NCs   = (size_t)NROWS * CH;
  ushort* R0    = wsu;                                // h_ln -> V^T -> h2 (bf16)
  ushort* QKV   = wsu + NCs;                          // 8192 x 4608 bf16
  ushort* wqkvT = wsu + NCs + (size_t)NROWS * QKVLD;  // 4608 x 1536 bf16
  ushort* woT   = wqkvT + (size_t)QKVLD * CH;         // 1536 x 1536 bf16
  float*  meanp = (float*)(woT + (size_t)CH * CH);
  float*  rstdp = meanp + SEQ;
  ushort* w1T   = QKV;                                // reuse after attention
  ushort* w2T   = QKV + (size_t)FFDIM * CH;
  ushort* FF1   = QKV + 2 * (size_t)FFDIM * CH;

  const dim3 blk(256);

  transpose_cast<<<dim3(HD / 32, CH / 32, NH), blk, 0, stream>>>(
      wq, wqkvT, CH, HD, CH, (long)CH * HD, (long)HD * CH);
  transpose_cast<<<dim3(HD / 32, CH / 32, NH), blk, 0, stream>>>(
      wk, wqkvT + (size_t)CH * CH, CH, HD, CH, (long)CH * HD, (long)HD * CH);
  transpose_cast<<<dim3(HD / 32, CH / 32, NH), blk, 0, stream>>>(
      wv, wqkvT + 2 * (size_t)CH * CH, CH, HD, CH, (long)CH * HD, (long)HD * CH);
  transpose_cast<<<dim3(CH / 32, CH / 32, 1), blk, 0, stream>>>(
      wo, woT, CH, CH, CH, 0, 0);

  // 1. h_ln = LN1(x) -> R0 (bf16)
  ln_bf16<<<NROWS, blk, 0, stream>>>(x, ln1g, ln1b, R0);

  // 2. fused QKV GEMM
  gemm_bf16<0, 0, 0, 1><<<dim3(QKVLD / BT, NROWS / BT), blk, 0, stream>>>(
      R0, CH, wqkvT, CH, QKV, QKVLD, nullptr, nullptr, 0, CH);

  // 2b. V^T into R0 (h_ln is dead after the QKV GEMM)
  transpose_v<<<dim3(SEQ / 32, HD / 32, BATCH * NH), blk, 0, stream>>>(
      QKV + 2 * CH, R0);

  // 3. o = flash_attn(q,k,v^T) -> Q slot of QKV (block-private, Q consumed first)
  flash_attn_mfma<<<dim3(SEQ / FQT, BATCH * NH), blk, 0, stream>>>(
      QKV, QKV + CH, R0, QKV, QKVLD, QKVLD);

  // 4. x1 = x + o @ wo + bo -> out (fp32)
  gemm_bf16<0, 1, 1, 0><<<dim3(CH / BT, NROWS / BT), blk, 0, stream>>>(
      QKV, QKVLD, woT, CH, out, CH, bo, x, CH, CH);

  // FF weight prep (QKV region dead only now, after the projection)
  transpose_cast<<<dim3(FFDIM / 32, CH / 32, 1), blk, 0, stream>>>(
      w1, w1T, CH, FFDIM, CH, 0, 0);
  transpose_cast<<<dim3(CH / 32, FFDIM / 32, 1), blk, 0, stream>>>(
      w2, w2T, FFDIM, CH, FFDIM, 0, 0);

  // 5. BN1 in place on out
  bn_stats<<<SEQ, blk, 0, stream>>>(out, meanp, rstdp);
  bn_apply<<<(NROWS * CH) / 256, blk, 0, stream>>>(out, out, meanp, rstdp, bn1g, bn1b);

  // 6. h2 = LN2(x1) -> R0 (bf16)
  ln_bf16<<<NROWS, blk, 0, stream>>>(out, ln2g, ln2b, R0);

  // 7. FF in 2 row-chunks of 4096
  constexpr int FFC = 4096;
  for (int c = 0; c < NROWS / FFC; ++c) {
    const size_t r0 = (size_t)c * FFC;
    gemm_bf16<1, 1, 0, 1><<<dim3(FFDIM / BT, FFC / BT), blk, 0, stream>>>(
        R0 + r0 * CH, CH, w1T, CH, FF1, FFDIM, b1, nullptr, 0, CH);
    gemm_bf16<0, 1, 1, 0><<<dim3(CH / BT, FFC / BT), blk, 0, stream>>>(
        FF1, FFDIM, w2T, FFDIM, out + r0 * CH, CH, b2, out + r0 * CH, CH, FFDIM);
  }

  // 8. BN2 in place on out
  bn_stats<<<SEQ, blk, 0, stream>>>(out, meanp, rstdp);
  bn_apply<<<(NROWS * CH) / 256, blk, 0, stream>>>(out, out, meanp, rstdp, bn2g, bn2b);
}

// Round 3
// 1277.331 us; speedup vs baseline: 1.1944x; 1.1944x over previous
//
#include <hip/hip_runtime.h>
#include <hip/hip_bf16.h>

// Problem constants
constexpr int BATCH = 8;
constexpr int SEQ   = 1024;
constexpr int CH    = 1536;
constexpr int NH    = 12;
constexpr int HD    = 128;       // head dim
constexpr int FFDIM = 6144;      // 4*CH
constexpr int NROWS = BATCH * SEQ;   // 8192
constexpr int QKVLD = 3 * CH;    // 4608, fused QKV row stride
constexpr float EPS = 1e-5f;

typedef unsigned short ushort;
typedef __attribute__((ext_vector_type(8))) ushort us8;
typedef __attribute__((ext_vector_type(8))) __bf16 bf16x8;
typedef __attribute__((ext_vector_type(4))) float f32x4;

__device__ __forceinline__ float b2f(ushort u) {
  return __uint_as_float(((unsigned)u) << 16);
}
__device__ __forceinline__ ushort f2b(float f) {
  __hip_bfloat16 h = __float2bfloat16(f);  // RNE
  return *reinterpret_cast<ushort*>(&h);
}

// async global->LDS, 16 bytes per lane. LDS dest = wave-uniform base + lane*16.
__device__ __forceinline__ void g2l16(const ushort* g, ushort* l) {
  __builtin_amdgcn_global_load_lds(
      (const __attribute__((address_space(1))) void*)g,
      (__attribute__((address_space(3))) void*)l, 16, 0, 0);
}

// ---------------- block reduction helper (blockDim == 256) ----------------
__device__ __forceinline__ float block_sum(float v, float* red) {
#pragma unroll
  for (int o = 32; o > 0; o >>= 1) v += __shfl_down(v, o, 64);
  const int w = threadIdx.x >> 6;
  if ((threadIdx.x & 63) == 0) red[w] = v;
  __syncthreads();
  const float r = red[0] + red[1] + red[2] + red[3];
  __syncthreads();
  return r;
}

// ---------------- LayerNorm over last dim (CH), bf16 output ----------------
__global__ __launch_bounds__(256) void ln_bf16(const float* __restrict__ x,
                                               const float* __restrict__ g,
                                               const float* __restrict__ b,
                                               ushort* __restrict__ out) {
  __shared__ float row[CH];
  __shared__ float red[4];
  const size_t base = (size_t)blockIdx.x * CH;
  float s = 0.f;
  for (int c = threadIdx.x; c < CH; c += 256) {
    const float v = x[base + c];
    row[c] = v;
    s += v;
  }
  const float mean = block_sum(s, red) * (1.0f / CH);
  float s2 = 0.f;
  for (int c = threadIdx.x; c < CH; c += 256) {
    const float d = row[c] - mean;
    s2 += d * d;
  }
  const float var = block_sum(s2, red) * (1.0f / CH);
  const float rstd = rsqrtf(var + EPS);
  for (int c = threadIdx.x; c < CH; c += 256)
    out[base + c] = f2b((row[c] - mean) * rstd * g[c] + b[c]);
}

// ---------------- transpose + fp32->bf16 cast for weights ----------------
__global__ __launch_bounds__(256) void transpose_cast(const float* __restrict__ src,
                                                      ushort* __restrict__ dst,
                                                      int R, int Cc, int ldd,
                                                      long srcZ, long dstZ) {
  __shared__ float tile[32][33];
  src += (size_t)blockIdx.z * srcZ;
  dst += (size_t)blockIdx.z * dstZ;
  const int c0 = blockIdx.x * 32, r0 = blockIdx.y * 32;
  const int tx = threadIdx.x & 31, ty = threadIdx.x >> 5;  // 32 x 8
#pragma unroll
  for (int i = ty; i < 32; i += 8)
    tile[i][tx] = src[(size_t)(r0 + i) * Cc + c0 + tx];
  __syncthreads();
#pragma unroll
  for (int i = ty; i < 32; i += 8)
    dst[(size_t)(c0 + i) * ldd + r0 + tx] = f2b(tile[tx][i]);
}

// ---------------- bf16 V transpose: (b,t,h,d) -> (b,h,d,t) ----------------
__global__ __launch_bounds__(256) void transpose_v(const ushort* __restrict__ src,
                                                   ushort* __restrict__ dst) {
  __shared__ ushort tile[32][33];
  const int bh = blockIdx.z;
  const int b = bh / NH, h = bh % NH;
  const ushort* s = src + (size_t)b * SEQ * QKVLD + (size_t)h * HD;
  ushort* d = dst + (size_t)bh * HD * SEQ;
  const int t0 = blockIdx.x * 32, d0 = blockIdx.y * 32;
  const int tx = threadIdx.x & 31, ty = threadIdx.x >> 5;  // 32 x 8
#pragma unroll
  for (int i = ty; i < 32; i += 8)
    tile[i][tx] = s[(size_t)(t0 + i) * QKVLD + d0 + tx];   // tile[t][d]
  __syncthreads();
#pragma unroll
  for (int i = ty; i < 32; i += 8)
    d[(size_t)(d0 + i) * SEQ + t0 + tx] = tile[tx][i];     // dst[d][t]
}

// ---------------- bf16 MFMA GEMM (m97-style: global_load_lds staging) ------
// C[m,n] = sum_k A[m,k] * Bt[n,k]  (+bias[n]) (relu) (+res[m,n])
constexpr int BT = 128;   // tile M and N
constexpr int BK = 32;    // K tile (bf16)

template <int RELU, int BIAS, int RES, int OUTBF>
__global__ __launch_bounds__(256) void gemm_bf16(
    const ushort* __restrict__ A, int lda,
    const ushort* __restrict__ Bt, int ldb,
    void* __restrict__ Cm, int ldc,
    const float* __restrict__ bias,
    const float* __restrict__ res, int ldr,
    int K) {
  __shared__ ushort As[BT * BK];  // 8 KB
  __shared__ ushort Bs[BT * BK];  // 8 KB
  const int tid = threadIdx.x;
  const int lane = tid & 63;
  const int wv = tid >> 6;
  const int m0 = blockIdx.y * BT;
  const int n0 = blockIdx.x * BT;
  const int srow = wv * 32 + (lane >> 2);
  const int schunk = (lane & 3) * 8;
  const ushort* gA0 = A + (size_t)(m0 + srow) * lda + schunk;
  const ushort* gA1 = gA0 + (size_t)16 * lda;
  const ushort* gB0 = Bt + (size_t)(n0 + srow) * ldb + schunk;
  const ushort* gB1 = gB0 + (size_t)16 * ldb;
  ushort* lA0 = As + (wv * 32) * BK;
  ushort* lA1 = lA0 + 16 * BK;
  ushort* lB0 = Bs + (wv * 32) * BK;
  ushort* lB1 = lB0 + 16 * BK;
  const int wm = (wv >> 1) * 64, wn = (wv & 1) * 64;
  const int fr = lane & 15;
  const int quad = lane >> 4;
  const int koff = quad * 8;

  f32x4 acc[4][4] = {{}};
  for (int k0 = 0; k0 < K; k0 += BK) {
    __syncthreads();
    g2l16(gA0 + k0, lA0);
    g2l16(gA1 + k0, lA1);
    g2l16(gB0 + k0, lB0);
    g2l16(gB1 + k0, lB1);
    __syncthreads();
    bf16x8 af[4], bf[4];
#pragma unroll
    for (int mi = 0; mi < 4; ++mi)
      af[mi] = *(const bf16x8*)&As[(wm + mi * 16 + fr) * BK + koff];
#pragma unroll
    for (int ni = 0; ni < 4; ++ni)
      bf[ni] = *(const bf16x8*)&Bs[(wn + ni * 16 + fr) * BK + koff];
#pragma unroll
    for (int mi = 0; mi < 4; ++mi)
#pragma unroll
      for (int ni = 0; ni < 4; ++ni)
        acc[mi][ni] = __builtin_amdgcn_mfma_f32_16x16x32_bf16(af[mi], bf[ni], acc[mi][ni], 0, 0, 0);
  }
#pragma unroll
  for (int ni = 0; ni < 4; ++ni) {
    const int col = n0 + wn + ni * 16 + fr;
    const float bs = BIAS ? bias[col] : 0.f;
#pragma unroll
    for (int mi = 0; mi < 4; ++mi) {
      const int rowb = m0 + wm + mi * 16 + quad * 4;
#pragma unroll
      for (int r = 0; r < 4; ++r) {
        float v = acc[mi][ni][r] + bs;
        if (RELU) v = fmaxf(v, 0.f);
        const size_t idx = (size_t)(rowb + r) * ldc + col;
        if (RES) v += res[(size_t)(rowb + r) * ldr + col];
        if (OUTBF) ((ushort*)Cm)[idx] = f2b(v);
        else       ((float*)Cm)[idx] = v;
      }
    }
  }
}

// ---------------- MFMA flash attention v3: double-buffered LDS K/V --------
// K tile (64 keys x 128d) and V^T tile (128d x 64 keys) staged via
// global_load_lds (coalesced 1KB/inst), XOR-swizzled through pre-swizzled
// GLOBAL source addresses (g2l writes linearly; rule: same involution on
// both sides). Double-buffered: tile jt+1 issued before compute of jt,
// drained only at the end-of-iteration barrier -> global latency hides
// under QK^T+softmax+PV.
constexpr int FQT = 64;   // queries per block
constexpr int VLD = 72;   // Ps LDS row stride (ushorts)

__global__ __launch_bounds__(256) void flash_attn_mfma(
    const ushort* __restrict__ q, const ushort* __restrict__ k,
    const ushort* __restrict__ vt, ushort* __restrict__ o,
    int ld, int ldo) {
  __shared__ ushort Ks[2][64 * 128];   // 2 x 16 KB, swizzled
  __shared__ ushort Vs[2][128 * 64];   // 2 x 16 KB, swizzled
  __shared__ ushort Ps[4][16][VLD];    // 9.2 KB per-wave P tiles
  const int tid = threadIdx.x;
  const int lane = tid & 63;
  const int w = tid >> 6;
  const int fr = lane & 15;
  const int quad = lane >> 4;
  const int qt = blockIdx.x;
  const int b = blockIdx.y / NH;
  const int h = blockIdx.y % NH;
  const size_t base = (size_t)b * SEQ * ld + (size_t)h * HD;
  const ushort* vtb = vt + (size_t)(b * NH + h) * HD * SEQ;
  const int q0 = qt * FQT;
  const int qrow = q0 + w * 16;
  const float scale = 0.08838834764831845f;  // 1/sqrt(128)

  // Staging source pointers for tile jt=0. Each wave stages 16 K rows and
  // 32 V^T rows with 4+4 g2l16. Global chunk index pre-XORed so the linear
  // LDS write lands the swizzled layout.
  const ushort* gk[4];
  const ushort* gv[4];
#pragma unroll
  for (int t = 0; t < 4; ++t) {
    const int jr = w * 16 + t * 4 + (lane >> 4);        // K tile row 0..63
    const int kc = (lane & 15) ^ (jr & 7);              // chunk 0..15
    gk[t] = k + base + (size_t)jr * ld + kc * 8;
    const int dr = w * 32 + t * 8 + (lane >> 3);        // V^T tile row 0..127
    const int vc = (lane & 7) ^ (dr & 7);               // chunk 0..7
    gv[t] = vtb + (size_t)dr * SEQ + vc * 8;
  }

  bf16x8 aq[4];
  {
    const ushort* qp = q + base + (size_t)(qrow + fr) * ld + quad * 8;
#pragma unroll
    for (int ks = 0; ks < 4; ++ks) aq[ks] = *(const bf16x8*)(qp + ks * 32);
  }

  float m_i[4], l_i[4];
  f32x4 oacc[8];
#pragma unroll
  for (int i = 0; i < 4; ++i) { m_i[i] = -3.0e38f; l_i[i] = 0.f; }
#pragma unroll
  for (int n8 = 0; n8 < 8; ++n8) oacc[n8] = (f32x4){0.f, 0.f, 0.f, 0.f};

  // prologue: stage tile 0 into buffer 0
#pragma unroll
  for (int t = 0; t < 4; ++t) {
    g2l16(gk[t], &Ks[0][w * 2048 + t * 512]);
    g2l16(gv[t], &Vs[0][w * 2048 + t * 512]);
  }
  __syncthreads();   // drains vmcnt -> tile 0 visible

  int cur = 0;
  for (int jt = 0; jt <= qt; ++jt) {
    const int j0 = jt * FQT;
    // issue next tile's staging into the other buffer (overlaps with compute)
    if (jt < qt) {
      const size_t ko = (size_t)(jt + 1) * FQT * ld;
      const int vo = (jt + 1) * FQT;
      ushort* kd = (cur ? &Ks[0][0] : &Ks[1][0]) + w * 2048;
      ushort* vd = (cur ? &Vs[0][0] : &Vs[1][0]) + w * 2048;
#pragma unroll
      for (int t = 0; t < 4; ++t) {
        g2l16(gk[t] + ko, kd + t * 512);
        g2l16(gv[t] + vo, vd + t * 512);
      }
    }
    const ushort* Kc = cur ? &Ks[1][0] : &Ks[0][0];
    const ushort* Vc = cur ? &Vs[1][0] : &Vs[0][0];

    // QK^T from swizzled LDS K tile
    f32x4 sacc[4];
#pragma unroll
    for (int ni = 0; ni < 4; ++ni) sacc[ni] = (f32x4){0.f, 0.f, 0.f, 0.f};
#pragma unroll
    for (int ks = 0; ks < 4; ++ks) {
#pragma unroll
      for (int ni = 0; ni < 4; ++ni) {
        const int j = ni * 16 + fr;
        const int s = (ks * 4 + quad) ^ (fr & 7);
        const bf16x8 kf = *(const bf16x8*)&Kc[j * 128 + s * 8];
        sacc[ni] = __builtin_amdgcn_mfma_f32_16x16x32_bf16(aq[ks], kf, sacc[ni], 0, 0, 0);
      }
    }
    const bool diag = (jt == qt);
    float alpha[4];
#pragma unroll
    for (int i = 0; i < 4; ++i) {
      const int qg = qrow + quad * 4 + i;
      float pv[4];
      float vmax = -3.0e38f;
#pragma unroll
      for (int ni = 0; ni < 4; ++ni) {
        float sv = sacc[ni][i] * scale;
        if (diag && (j0 + ni * 16 + fr > qg)) sv = -3.0e38f;
        pv[ni] = sv;
        vmax = fmaxf(vmax, sv);
      }
#pragma unroll
      for (int mm = 8; mm >= 1; mm >>= 1) vmax = fmaxf(vmax, __shfl_xor(vmax, mm, 64));
      const float m_new = fmaxf(m_i[i], vmax);
      alpha[i] = __expf(m_i[i] - m_new);
      m_i[i] = m_new;
      float rsum = 0.f;
#pragma unroll
      for (int ni = 0; ni < 4; ++ni) {
        const float pe = __expf(pv[ni] - m_new);
        Ps[w][quad * 4 + i][ni * 16 + fr] = f2b(pe);
        rsum += pe;
      }
#pragma unroll
      for (int mm = 8; mm >= 1; mm >>= 1) rsum += __shfl_xor(rsum, mm, 64);
      l_i[i] = l_i[i] * alpha[i] + rsum;
#pragma unroll
      for (int n8 = 0; n8 < 8; ++n8) oacc[n8][i] *= alpha[i];
    }
    // PV from swizzled LDS V^T tile
#pragma unroll
    for (int js = 0; js < 2; ++js) {
      const bf16x8 pf = *(const bf16x8*)&Ps[w][fr][js * 32 + quad * 8];
#pragma unroll
      for (int n8 = 0; n8 < 8; ++n8) {
        const int d = n8 * 16 + fr;
        const int s = (js * 4 + quad) ^ (fr & 7);
        const bf16x8 vf = *(const bf16x8*)&Vc[d * 64 + s * 8];
        oacc[n8] = __builtin_amdgcn_mfma_f32_16x16x32_bf16(pf, vf, oacc[n8], 0, 0, 0);
      }
    }
    __syncthreads();   // drains prefetch vmcnt; all waves done with buf[cur]
    cur ^= 1;
  }
#pragma unroll
  for (int i = 0; i < 4; ++i) {
    const float inv = 1.0f / l_i[i];
    ushort* op = o + ((size_t)b * SEQ + qrow + quad * 4 + i) * ldo + (size_t)h * HD;
#pragma unroll
    for (int n8 = 0; n8 < 8; ++n8) op[n8 * 16 + fr] = f2b(oacc[n8][i] * inv);
  }
}

// ---------------- BatchNorm over (B, C) per T channel (fp32) ----------------
__global__ __launch_bounds__(256) void bn_stats(const float* __restrict__ x,
                                                float* __restrict__ mean,
                                                float* __restrict__ rstd) {
  __shared__ float red[4];
  const int t = blockIdx.x;
  float s = 0.f;
  for (int bb = 0; bb < BATCH; ++bb) {
    const float* p = x + ((size_t)bb * SEQ + t) * CH;
    for (int c = threadIdx.x; c < CH; c += 256) s += p[c];
  }
  const float m = block_sum(s, red) * (1.0f / (BATCH * CH));
  float s2 = 0.f;
  for (int bb = 0; bb < BATCH; ++bb) {
    const float* p = x + ((size_t)bb * SEQ + t) * CH;
    for (int c = threadIdx.x; c < CH; c += 256) {
      const float d = p[c] - m;
      s2 += d * d;
    }
  }
  const float var = block_sum(s2, red) * (1.0f / (BATCH * CH));
  if (threadIdx.x == 0) {
    mean[t] = m;
    rstd[t] = rsqrtf(var + EPS);
  }
}

__global__ __launch_bounds__(256) void bn_apply(const float* __restrict__ x,
                                                float* __restrict__ out,
                                                const float* __restrict__ mean,
                                                const float* __restrict__ rstd,
                                                const float* __restrict__ g,
                                                const float* __restrict__ bb) {
  const size_t i = (size_t)blockIdx.x * 256 + threadIdx.x;
  const int t = (int)((i / CH) % SEQ);
  out[i] = (x[i] - mean[t]) * rstd[t] * g[t] + bb[t];
}

// ---------------- launch ----------------
extern "C" void kernel_launch(void* const* d_in, const int* in_sizes, int n_in,
                              void* d_out, int out_size, void* d_ws, size_t ws_size,
                              hipStream_t stream) {
  const float* x    = (const float*)d_in[0];
  const float* wq   = (const float*)d_in[1];
  const float* wk   = (const float*)d_in[2];
  const float* wv   = (const float*)d_in[3];
  const float* wo   = (const float*)d_in[4];
  const float* bo   = (const float*)d_in[5];
  const float* ln1g = (const float*)d_in[6];
  const float* ln1b = (const float*)d_in[7];
  const float* ln2g = (const float*)d_in[8];
  const float* ln2b = (const float*)d_in[9];
  const float* w1   = (const float*)d_in[10];
  const float* b1   = (const float*)d_in[11];
  const float* w2   = (const float*)d_in[12];
  const float* b2   = (const float*)d_in[13];
  const float* bn1g = (const float*)d_in[14];
  const float* bn1b = (const float*)d_in[15];
  const float* bn2g = (const float*)d_in[16];
  const float* bn2b = (const float*)d_in[17];
  float* out = (float*)d_out;   // X1 fp32 residual stream lives here

  // Workspace (ushort units). Peak ~119.6 MB.
  ushort* wsu = (ushort*)d_ws;
  const size_t NCs   = (size_t)NROWS * CH;
  ushort* R0    = wsu;                                // h_ln -> V^T -> h2 (bf16)
  ushort* QKV   = wsu + NCs;                          // 8192 x 4608 bf16
  ushort* wqkvT = wsu + NCs + (size_t)NROWS * QKVLD;  // 4608 x 1536 bf16
  ushort* woT   = wqkvT + (size_t)QKVLD * CH;         // 1536 x 1536 bf16
  float*  meanp = (float*)(woT + (size_t)CH * CH);
  float*  rstdp = meanp + SEQ;
  ushort* w1T   = QKV;                                // reuse after attention
  ushort* w2T   = QKV + (size_t)FFDIM * CH;
  ushort* FF1   = QKV + 2 * (size_t)FFDIM * CH;

  const dim3 blk(256);

  transpose_cast<<<dim3(HD / 32, CH / 32, NH), blk, 0, stream>>>(
      wq, wqkvT, CH, HD, CH, (long)CH * HD, (long)HD * CH);
  transpose_cast<<<dim3(HD / 32, CH / 32, NH), blk, 0, stream>>>(
      wk, wqkvT + (size_t)CH * CH, CH, HD, CH, (long)CH * HD, (long)HD * CH);
  transpose_cast<<<dim3(HD / 32, CH / 32, NH), blk, 0, stream>>>(
      wv, wqkvT + 2 * (size_t)CH * CH, CH, HD, CH, (long)CH * HD, (long)HD * CH);
  transpose_cast<<<dim3(CH / 32, CH / 32, 1), blk, 0, stream>>>(
      wo, woT, CH, CH, CH, 0, 0);

  // 1. h_ln = LN1(x) -> R0 (bf16)
  ln_bf16<<<NROWS, blk, 0, stream>>>(x, ln1g, ln1b, R0);

  // 2. fused QKV GEMM
  gemm_bf16<0, 0, 0, 1><<<dim3(QKVLD / BT, NROWS / BT), blk, 0, stream>>>(
      R0, CH, wqkvT, CH, QKV, QKVLD, nullptr, nullptr, 0, CH);

  // 2b. V^T into R0 (h_ln is dead after the QKV GEMM)
  transpose_v<<<dim3(SEQ / 32, HD / 32, BATCH * NH), blk, 0, stream>>>(
      QKV + 2 * CH, R0);

  // 3. o = flash_attn(q,k,v^T) -> Q slot of QKV (block-private, Q consumed first)
  flash_attn_mfma<<<dim3(SEQ / FQT, BATCH * NH), blk, 0, stream>>>(
      QKV, QKV + CH, R0, QKV, QKVLD, QKVLD);

  // 4. x1 = x + o @ wo + bo -> out (fp32)
  gemm_bf16<0, 1, 1, 0><<<dim3(CH / BT, NROWS / BT), blk, 0, stream>>>(
      QKV, QKVLD, woT, CH, out, CH, bo, x, CH, CH);

  // FF weight prep (QKV region dead only now, after the projection)
  transpose_cast<<<dim3(FFDIM / 32, CH / 32, 1), blk, 0, stream>>>(
      w1, w1T, CH, FFDIM, CH, 0, 0);
  transpose_cast<<<dim3(CH / 32, FFDIM / 32, 1), blk, 0, stream>>>(
      w2, w2T, FFDIM, CH, FFDIM, 0, 0);

  // 5. BN1 in place on out
  bn_stats<<<SEQ, blk, 0, stream>>>(out, meanp, rstdp);
  bn_apply<<<(NROWS * CH) / 256, blk, 0, stream>>>(out, out, meanp, rstdp, bn1g, bn1b);

  // 6. h2 = LN2(x1) -> R0 (bf16)
  ln_bf16<<<NROWS, blk, 0, stream>>>(out, ln2g, ln2b, R0);

  // 7. FF in 2 row-chunks of 4096
  constexpr int FFC = 4096;
  for (int c = 0; c < NROWS / FFC; ++c) {
    const size_t r0 = (size_t)c * FFC;
    gemm_bf16<1, 1, 0, 1><<<dim3(FFDIM / BT, FFC / BT), blk, 0, stream>>>(
        R0 + r0 * CH, CH, w1T, CH, FF1, FFDIM, b1, nullptr, 0, CH);
    gemm_bf16<0, 1, 1, 0><<<dim3(CH / BT, FFC / BT), blk, 0, stream>>>(
        FF1, FFDIM, w2T, FFDIM, out + r0 * CH, CH, b2, out + r0 * CH, CH, FFDIM);
  }

  // 8. BN2 in place on out
  bn_stats<<<SEQ, blk, 0, stream>>>(out, meanp, rstdp);
  bn_apply<<<(NROWS * CH) / 256, blk, 0, stream>>>(out, out, meanp, rstdp, bn2g, bn2b);
}

// Round 5
// 1181.890 us; speedup vs baseline: 1.2908x; 1.0808x over previous
//
#include <hip/hip_runtime.h>
#include <hip/hip_bf16.h>

// Problem constants
constexpr int BATCH = 8;
constexpr int SEQ   = 1024;
constexpr int CH    = 1536;
constexpr int NH    = 12;
constexpr int HD    = 128;       // head dim
constexpr int FFDIM = 6144;      // 4*CH
constexpr int NROWS = BATCH * SEQ;   // 8192
constexpr int QKVLD = 3 * CH;    // 4608, fused QKV row stride
constexpr float EPS = 1e-5f;

typedef unsigned short ushort;
typedef __attribute__((ext_vector_type(8))) ushort us8;
typedef __attribute__((ext_vector_type(8))) __bf16 bf16x8;
typedef __attribute__((ext_vector_type(4))) float f32x4;

__device__ __forceinline__ float b2f(ushort u) {
  return __uint_as_float(((unsigned)u) << 16);
}
__device__ __forceinline__ ushort f2b(float f) {
  __hip_bfloat16 h = __float2bfloat16(f);  // RNE
  return *reinterpret_cast<ushort*>(&h);
}

// async global->LDS, 16 bytes per lane. LDS dest = wave-uniform base + lane*16.
__device__ __forceinline__ void g2l16(const ushort* g, ushort* l) {
  __builtin_amdgcn_global_load_lds(
      (const __attribute__((address_space(1))) void*)g,
      (__attribute__((address_space(3))) void*)l, 16, 0, 0);
}

// ---------------- block reduction helper (blockDim == 256) ----------------
__device__ __forceinline__ float block_sum(float v, float* red) {
#pragma unroll
  for (int o = 32; o > 0; o >>= 1) v += __shfl_down(v, o, 64);
  const int w = threadIdx.x >> 6;
  if ((threadIdx.x & 63) == 0) red[w] = v;
  __syncthreads();
  const float r = red[0] + red[1] + red[2] + red[3];
  __syncthreads();
  return r;
}

// ---------------- LayerNorm over last dim (CH), bf16 output ----------------
__global__ __launch_bounds__(256) void ln_bf16(const float* __restrict__ x,
                                               const float* __restrict__ g,
                                               const float* __restrict__ b,
                                               ushort* __restrict__ out) {
  __shared__ float row[CH];
  __shared__ float red[4];
  const size_t base = (size_t)blockIdx.x * CH;
  float s = 0.f;
  for (int c = threadIdx.x; c < CH; c += 256) {
    const float v = x[base + c];
    row[c] = v;
    s += v;
  }
  const float mean = block_sum(s, red) * (1.0f / CH);
  float s2 = 0.f;
  for (int c = threadIdx.x; c < CH; c += 256) {
    const float d = row[c] - mean;
    s2 += d * d;
  }
  const float var = block_sum(s2, red) * (1.0f / CH);
  const float rstd = rsqrtf(var + EPS);
  for (int c = threadIdx.x; c < CH; c += 256)
    out[base + c] = f2b((row[c] - mean) * rstd * g[c] + b[c]);
}

// ---------------- transpose + fp32->bf16 cast for weights ----------------
__global__ __launch_bounds__(256) void transpose_cast(const float* __restrict__ src,
                                                      ushort* __restrict__ dst,
                                                      int R, int Cc, int ldd,
                                                      long srcZ, long dstZ) {
  __shared__ float tile[32][33];
  src += (size_t)blockIdx.z * srcZ;
  dst += (size_t)blockIdx.z * dstZ;
  const int c0 = blockIdx.x * 32, r0 = blockIdx.y * 32;
  const int tx = threadIdx.x & 31, ty = threadIdx.x >> 5;  // 32 x 8
#pragma unroll
  for (int i = ty; i < 32; i += 8)
    tile[i][tx] = src[(size_t)(r0 + i) * Cc + c0 + tx];
  __syncthreads();
#pragma unroll
  for (int i = ty; i < 32; i += 8)
    dst[(size_t)(c0 + i) * ldd + r0 + tx] = f2b(tile[tx][i]);
}

// ---------------- bf16 V transpose: (b,t,h,d) -> (b,h,d,t) ----------------
__global__ __launch_bounds__(256) void transpose_v(const ushort* __restrict__ src,
                                                   ushort* __restrict__ dst) {
  __shared__ ushort tile[32][33];
  const int bh = blockIdx.z;
  const int b = bh / NH, h = bh % NH;
  const ushort* s = src + (size_t)b * SEQ * QKVLD + (size_t)h * HD;
  ushort* d = dst + (size_t)bh * HD * SEQ;
  const int t0 = blockIdx.x * 32, d0 = blockIdx.y * 32;
  const int tx = threadIdx.x & 31, ty = threadIdx.x >> 5;  // 32 x 8
#pragma unroll
  for (int i = ty; i < 32; i += 8)
    tile[i][tx] = s[(size_t)(t0 + i) * QKVLD + d0 + tx];   // tile[t][d]
  __syncthreads();
#pragma unroll
  for (int i = ty; i < 32; i += 8)
    d[(size_t)(d0 + i) * SEQ + t0 + tx] = tile[tx][i];     // dst[d][t]
}

// ---------------- bf16 MFMA GEMM v2: prefetch-pipelined + swizzled --------
// C[m,n] = sum_k A[m,k] * Bt[n,k]  (+bias[n]) (relu) (+res[m,n])
// 128x128 tile, BK=32, double-buffered LDS: next K-tile's global_load_lds
// issued BEFORE current tile's ds_read+MFMA; one barrier per K-step drains
// the prefetch after compute. LDS layout XOR-swizzled via pre-swizzled
// global source (chunk ^ ((row>>1)&3)) and matching read slot: quarter-wave
// conflicts 8-way -> 2-way (free). ATOMIC=1: split-K over blockIdx.z with
// fp32 atomicAdd epilogue (bias only from z==0; K arg = per-split K).
constexpr int BT = 128;   // tile M and N
constexpr int BK = 32;    // K tile (bf16)

template <int RELU, int BIAS, int RES, int OUTBF, int ATOMIC = 0>
__global__ __launch_bounds__(256) void gemm_bf16(
    const ushort* __restrict__ A, int lda,
    const ushort* __restrict__ Bt, int ldb,
    void* __restrict__ Cm, int ldc,
    const float* __restrict__ bias,
    const float* __restrict__ res, int ldr,
    int K) {
  __shared__ ushort As[2][BT * BK];  // 2 x 8 KB
  __shared__ ushort Bs[2][BT * BK];  // 2 x 8 KB
  const int tid = threadIdx.x;
  const int lane = tid & 63;
  const int wv = tid >> 6;
  const int m0 = blockIdx.y * BT;
  const int n0 = blockIdx.x * BT;
  if (ATOMIC) {
    const size_t kz = (size_t)blockIdx.z * K;
    A += kz;
    Bt += kz;
  }
  // staging: wave wv covers tile rows [wv*32, wv*32+32), 2 insts of 16 rows
  const int srow = wv * 32 + (lane >> 2);
  const int sx = (srow >> 1) & 3;                 // stage-side swizzle
  const int schunk = ((lane & 3) ^ sx) * 8;       // pre-swizzled global chunk
  const ushort* gA0 = A + (size_t)(m0 + srow) * lda + schunk;
  const ushort* gA1 = gA0 + (size_t)16 * lda;
  const ushort* gB0 = Bt + (size_t)(n0 + srow) * ldb + schunk;
  const ushort* gB1 = gB0 + (size_t)16 * ldb;
  const int lofs = (wv * 32) * BK;                // wave-uniform LDS offset
  // compute mapping
  const int wm = (wv >> 1) * 64, wn = (wv & 1) * 64;
  const int fr = lane & 15;
  const int quad = lane >> 4;
  const int koff = (quad ^ ((fr >> 1) & 3)) * 8;  // swizzled read slot

  f32x4 acc[4][4] = {{}};
  // prologue: stage K-tile 0 into buffer 0
  g2l16(gA0, &As[0][lofs]);
  g2l16(gA1, &As[0][lofs + 16 * BK]);
  g2l16(gB0, &Bs[0][lofs]);
  g2l16(gB1, &Bs[0][lofs + 16 * BK]);
  __syncthreads();
  int buf = 0;
  for (int k0 = 0; k0 < K; k0 += BK) {
    const int nk = k0 + BK;
    if (nk < K) {  // issue next tile's staging (overlaps with compute below)
      g2l16(gA0 + nk, &As[buf ^ 1][lofs]);
      g2l16(gA1 + nk, &As[buf ^ 1][lofs + 16 * BK]);
      g2l16(gB0 + nk, &Bs[buf ^ 1][lofs]);
      g2l16(gB1 + nk, &Bs[buf ^ 1][lofs + 16 * BK]);
    }
    bf16x8 af[4], bf[4];
#pragma unroll
    for (int mi = 0; mi < 4; ++mi)
      af[mi] = *(const bf16x8*)&As[buf][(wm + mi * 16 + fr) * BK + koff];
#pragma unroll
    for (int ni = 0; ni < 4; ++ni)
      bf[ni] = *(const bf16x8*)&Bs[buf][(wn + ni * 16 + fr) * BK + koff];
#pragma unroll
    for (int mi = 0; mi < 4; ++mi)
#pragma unroll
      for (int ni = 0; ni < 4; ++ni)
        acc[mi][ni] = __builtin_amdgcn_mfma_f32_16x16x32_bf16(af[mi], bf[ni], acc[mi][ni], 0, 0, 0);
    __syncthreads();  // drains prefetch vmcnt + all waves done reading buf
    buf ^= 1;
  }
  // epilogue: C/D layout col=lane&15, row=quad*4+reg
#pragma unroll
  for (int ni = 0; ni < 4; ++ni) {
    const int col = n0 + wn + ni * 16 + fr;
    const float bs = (BIAS && (!ATOMIC || blockIdx.z == 0)) ? bias[col] : 0.f;
#pragma unroll
    for (int mi = 0; mi < 4; ++mi) {
      const int rowb = m0 + wm + mi * 16 + quad * 4;
#pragma unroll
      for (int r = 0; r < 4; ++r) {
        float v = acc[mi][ni][r] + bs;
        if (RELU) v = fmaxf(v, 0.f);
        const size_t idx = (size_t)(rowb + r) * ldc + col;
        if (RES) v += res[(size_t)(rowb + r) * ldr + col];
        if (ATOMIC)      atomicAdd((float*)Cm + idx, v);
        else if (OUTBF)  ((ushort*)Cm)[idx] = f2b(v);
        else             ((float*)Cm)[idx] = v;
      }
    }
  }
}

// ---------------- MFMA flash attention v3: double-buffered LDS K/V --------
constexpr int FQT = 64;   // queries per block
constexpr int VLD = 72;   // Ps LDS row stride (ushorts)

__global__ __launch_bounds__(256) void flash_attn_mfma(
    const ushort* __restrict__ q, const ushort* __restrict__ k,
    const ushort* __restrict__ vt, ushort* __restrict__ o,
    int ld, int ldo) {
  __shared__ ushort Ks[2][64 * 128];   // 2 x 16 KB, swizzled
  __shared__ ushort Vs[2][128 * 64];   // 2 x 16 KB, swizzled
  __shared__ ushort Ps[4][16][VLD];    // 9.2 KB per-wave P tiles
  const int tid = threadIdx.x;
  const int lane = tid & 63;
  const int w = tid >> 6;
  const int fr = lane & 15;
  const int quad = lane >> 4;
  const int qt = blockIdx.x;
  const int b = blockIdx.y / NH;
  const int h = blockIdx.y % NH;
  const size_t base = (size_t)b * SEQ * ld + (size_t)h * HD;
  const ushort* vtb = vt + (size_t)(b * NH + h) * HD * SEQ;
  const int q0 = qt * FQT;
  const int qrow = q0 + w * 16;
  const float scale = 0.08838834764831845f;  // 1/sqrt(128)

  const ushort* gk[4];
  const ushort* gv[4];
#pragma unroll
  for (int t = 0; t < 4; ++t) {
    const int jr = w * 16 + t * 4 + (lane >> 4);        // K tile row 0..63
    const int kc = (lane & 15) ^ (jr & 7);              // chunk 0..15
    gk[t] = k + base + (size_t)jr * ld + kc * 8;
    const int dr = w * 32 + t * 8 + (lane >> 3);        // V^T tile row 0..127
    const int vc = (lane & 7) ^ (dr & 7);               // chunk 0..7
    gv[t] = vtb + (size_t)dr * SEQ + vc * 8;
  }

  bf16x8 aq[4];
  {
    const ushort* qp = q + base + (size_t)(qrow + fr) * ld + quad * 8;
#pragma unroll
    for (int ks = 0; ks < 4; ++ks) aq[ks] = *(const bf16x8*)(qp + ks * 32);
  }

  float m_i[4], l_i[4];
  f32x4 oacc[8];
#pragma unroll
  for (int i = 0; i < 4; ++i) { m_i[i] = -3.0e38f; l_i[i] = 0.f; }
#pragma unroll
  for (int n8 = 0; n8 < 8; ++n8) oacc[n8] = (f32x4){0.f, 0.f, 0.f, 0.f};

  // prologue: stage tile 0 into buffer 0
#pragma unroll
  for (int t = 0; t < 4; ++t) {
    g2l16(gk[t], &Ks[0][w * 2048 + t * 512]);
    g2l16(gv[t], &Vs[0][w * 2048 + t * 512]);
  }
  __syncthreads();   // drains vmcnt -> tile 0 visible

  int cur = 0;
  for (int jt = 0; jt <= qt; ++jt) {
    const int j0 = jt * FQT;
    if (jt < qt) {
      const size_t ko = (size_t)(jt + 1) * FQT * ld;
      const int vo = (jt + 1) * FQT;
      ushort* kd = (cur ? &Ks[0][0] : &Ks[1][0]) + w * 2048;
      ushort* vd = (cur ? &Vs[0][0] : &Vs[1][0]) + w * 2048;
#pragma unroll
      for (int t = 0; t < 4; ++t) {
        g2l16(gk[t] + ko, kd + t * 512);
        g2l16(gv[t] + vo, vd + t * 512);
      }
    }
    const ushort* Kc = cur ? &Ks[1][0] : &Ks[0][0];
    const ushort* Vc = cur ? &Vs[1][0] : &Vs[0][0];

    // QK^T from swizzled LDS K tile
    f32x4 sacc[4];
#pragma unroll
    for (int ni = 0; ni < 4; ++ni) sacc[ni] = (f32x4){0.f, 0.f, 0.f, 0.f};
#pragma unroll
    for (int ks = 0; ks < 4; ++ks) {
#pragma unroll
      for (int ni = 0; ni < 4; ++ni) {
        const int j = ni * 16 + fr;
        const int s = (ks * 4 + quad) ^ (fr & 7);
        const bf16x8 kf = *(const bf16x8*)&Kc[j * 128 + s * 8];
        sacc[ni] = __builtin_amdgcn_mfma_f32_16x16x32_bf16(aq[ks], kf, sacc[ni], 0, 0, 0);
      }
    }
    const bool diag = (jt == qt);
    float alpha[4];
#pragma unroll
    for (int i = 0; i < 4; ++i) {
      const int qg = qrow + quad * 4 + i;
      float pv[4];
      float vmax = -3.0e38f;
#pragma unroll
      for (int ni = 0; ni < 4; ++ni) {
        float sv = sacc[ni][i] * scale;
        if (diag && (j0 + ni * 16 + fr > qg)) sv = -3.0e38f;
        pv[ni] = sv;
        vmax = fmaxf(vmax, sv);
      }
#pragma unroll
      for (int mm = 8; mm >= 1; mm >>= 1) vmax = fmaxf(vmax, __shfl_xor(vmax, mm, 64));
      const float m_new = fmaxf(m_i[i], vmax);
      alpha[i] = __expf(m_i[i] - m_new);
      m_i[i] = m_new;
      float rsum = 0.f;
#pragma unroll
      for (int ni = 0; ni < 4; ++ni) {
        const float pe = __expf(pv[ni] - m_new);
        Ps[w][quad * 4 + i][ni * 16 + fr] = f2b(pe);
        rsum += pe;
      }
#pragma unroll
      for (int mm = 8; mm >= 1; mm >>= 1) rsum += __shfl_xor(rsum, mm, 64);
      l_i[i] = l_i[i] * alpha[i] + rsum;
#pragma unroll
      for (int n8 = 0; n8 < 8; ++n8) oacc[n8][i] *= alpha[i];
    }
    // PV from swizzled LDS V^T tile
#pragma unroll
    for (int js = 0; js < 2; ++js) {
      const bf16x8 pf = *(const bf16x8*)&Ps[w][fr][js * 32 + quad * 8];
#pragma unroll
      for (int n8 = 0; n8 < 8; ++n8) {
        const int d = n8 * 16 + fr;
        const int s = (js * 4 + quad) ^ (fr & 7);
        const bf16x8 vf = *(const bf16x8*)&Vc[d * 64 + s * 8];
        oacc[n8] = __builtin_amdgcn_mfma_f32_16x16x32_bf16(pf, vf, oacc[n8], 0, 0, 0);
      }
    }
    __syncthreads();   // drains prefetch vmcnt; all waves done with buf[cur]
    cur ^= 1;
  }
#pragma unroll
  for (int i = 0; i < 4; ++i) {
    const float inv = 1.0f / l_i[i];
    ushort* op = o + ((size_t)b * SEQ + qrow + quad * 4 + i) * ldo + (size_t)h * HD;
#pragma unroll
    for (int n8 = 0; n8 < 8; ++n8) op[n8 * 16 + fr] = f2b(oacc[n8][i] * inv);
  }
}

// ---------------- BatchNorm over (B, C) per T channel (fp32) ----------------
__global__ __launch_bounds__(256) void bn_stats(const float* __restrict__ x,
                                                float* __restrict__ mean,
                                                float* __restrict__ rstd) {
  __shared__ float red[4];
  const int t = blockIdx.x;
  float s = 0.f;
  for (int bb = 0; bb < BATCH; ++bb) {
    const float* p = x + ((size_t)bb * SEQ + t) * CH;
    for (int c = threadIdx.x; c < CH; c += 256) s += p[c];
  }
  const float m = block_sum(s, red) * (1.0f / (BATCH * CH));
  float s2 = 0.f;
  for (int bb = 0; bb < BATCH; ++bb) {
    const float* p = x + ((size_t)bb * SEQ + t) * CH;
    for (int c = threadIdx.x; c < CH; c += 256) {
      const float d = p[c] - m;
      s2 += d * d;
    }
  }
  const float var = block_sum(s2, red) * (1.0f / (BATCH * CH));
  if (threadIdx.x == 0) {
    mean[t] = m;
    rstd[t] = rsqrtf(var + EPS);
  }
}

__global__ __launch_bounds__(256) void bn_apply(const float* __restrict__ x,
                                                float* __restrict__ out,
                                                const float* __restrict__ mean,
                                                const float* __restrict__ rstd,
                                                const float* __restrict__ g,
                                                const float* __restrict__ bb) {
  const size_t i = (size_t)blockIdx.x * 256 + threadIdx.x;
  const int t = (int)((i / CH) % SEQ);
  out[i] = (x[i] - mean[t]) * rstd[t] * g[t] + bb[t];
}

// ---------------- launch ----------------
extern "C" void kernel_launch(void* const* d_in, const int* in_sizes, int n_in,
                              void* d_out, int out_size, void* d_ws, size_t ws_size,
                              hipStream_t stream) {
  const float* x    = (const float*)d_in[0];
  const float* wq   = (const float*)d_in[1];
  const float* wk   = (const float*)d_in[2];
  const float* wv   = (const float*)d_in[3];
  const float* wo   = (const float*)d_in[4];
  const float* bo   = (const float*)d_in[5];
  const float* ln1g = (const float*)d_in[6];
  const float* ln1b = (const float*)d_in[7];
  const float* ln2g = (const float*)d_in[8];
  const float* ln2b = (const float*)d_in[9];
  const float* w1   = (const float*)d_in[10];
  const float* b1   = (const float*)d_in[11];
  const float* w2   = (const float*)d_in[12];
  const float* b2   = (const float*)d_in[13];
  const float* bn1g = (const float*)d_in[14];
  const float* bn1b = (const float*)d_in[15];
  const float* bn2g = (const float*)d_in[16];
  const float* bn2b = (const float*)d_in[17];
  float* out = (float*)d_out;   // X1 fp32 residual stream lives here

  // Workspace (ushort units). Peak ~119.6 MB.
  ushort* wsu = (ushort*)d_ws;
  const size_t NCs   = (size_t)NROWS * CH;
  ushort* R0    = wsu;                                // h_ln -> V^T -> h2 (bf16)
  ushort* QKV   = wsu + NCs;                          // 8192 x 4608 bf16
  ushort* wqkvT = wsu + NCs + (size_t)NROWS * QKVLD;  // 4608 x 1536 bf16
  ushort* woT   = wqkvT + (size_t)QKVLD * CH;         // 1536 x 1536 bf16
  float*  meanp = (float*)(woT + (size_t)CH * CH);
  float*  rstdp = meanp + SEQ;
  ushort* w1T   = QKV;                                // reuse after attention
  ushort* w2T   = QKV + (size_t)FFDIM * CH;
  ushort* FF1   = QKV + 2 * (size_t)FFDIM * CH;

  const dim3 blk(256);

  transpose_cast<<<dim3(HD / 32, CH / 32, NH), blk, 0, stream>>>(
      wq, wqkvT, CH, HD, CH, (long)CH * HD, (long)HD * CH);
  transpose_cast<<<dim3(HD / 32, CH / 32, NH), blk, 0, stream>>>(
      wk, wqkvT + (size_t)CH * CH, CH, HD, CH, (long)CH * HD, (long)HD * CH);
  transpose_cast<<<dim3(HD / 32, CH / 32, NH), blk, 0, stream>>>(
      wv, wqkvT + 2 * (size_t)CH * CH, CH, HD, CH, (long)CH * HD, (long)HD * CH);
  transpose_cast<<<dim3(CH / 32, CH / 32, 1), blk, 0, stream>>>(
      wo, woT, CH, CH, CH, 0, 0);

  // 1. h_ln = LN1(x) -> R0 (bf16)
  ln_bf16<<<NROWS, blk, 0, stream>>>(x, ln1g, ln1b, R0);

  // 2. fused QKV GEMM
  gemm_bf16<0, 0, 0, 1><<<dim3(QKVLD / BT, NROWS / BT), blk, 0, stream>>>(
      R0, CH, wqkvT, CH, QKV, QKVLD, nullptr, nullptr, 0, CH);

  // 2b. V^T into R0 (h_ln is dead after the QKV GEMM)
  transpose_v<<<dim3(SEQ / 32, HD / 32, BATCH * NH), blk, 0, stream>>>(
      QKV + 2 * CH, R0);

  // 3. o = flash_attn(q,k,v^T) -> Q slot of QKV (block-private, Q consumed first)
  flash_attn_mfma<<<dim3(SEQ / FQT, BATCH * NH), blk, 0, stream>>>(
      QKV, QKV + CH, R0, QKV, QKVLD, QKVLD);

  // 4. x1 = x + o @ wo + bo -> out (fp32)
  gemm_bf16<0, 1, 1, 0><<<dim3(CH / BT, NROWS / BT), blk, 0, stream>>>(
      QKV, QKVLD, woT, CH, out, CH, bo, x, CH, CH);

  // FF weight prep (QKV region dead only now, after the projection)
  transpose_cast<<<dim3(FFDIM / 32, CH / 32, 1), blk, 0, stream>>>(
      w1, w1T, CH, FFDIM, CH, 0, 0);
  transpose_cast<<<dim3(CH / 32, FFDIM / 32, 1), blk, 0, stream>>>(
      w2, w2T, FFDIM, CH, FFDIM, 0, 0);

  // 5. BN1 in place on out
  bn_stats<<<SEQ, blk, 0, stream>>>(out, meanp, rstdp);
  bn_apply<<<(NROWS * CH) / 256, blk, 0, stream>>>(out, out, meanp, rstdp, bn1g, bn1b);

  // 6. h2 = LN2(x1) -> R0 (bf16)
  ln_bf16<<<NROWS, blk, 0, stream>>>(out, ln2g, ln2b, R0);

  // 7. FF in 2 row-chunks of 4096. FF2 split-K=2 (grid 12x32x2 = 768 blocks
  // = 3/CU, vs 384 = 1.5/CU unsplit): fp32 atomicAdd onto out (holds x1).
  constexpr int FFC = 4096;
  for (int c = 0; c < NROWS / FFC; ++c) {
    const size_t r0 = (size_t)c * FFC;
    gemm_bf16<1, 1, 0, 1><<<dim3(FFDIM / BT, FFC / BT), blk, 0, stream>>>(
        R0 + r0 * CH, CH, w1T, CH, FF1, FFDIM, b1, nullptr, 0, CH);
    gemm_bf16<0, 1, 0, 0, 1><<<dim3(CH / BT, FFC / BT, 2), blk, 0, stream>>>(
        FF1, FFDIM, w2T, FFDIM, out + r0 * CH, CH, b2, nullptr, 0, FFDIM / 2);
  }

  // 8. BN2 in place on out
  bn_stats<<<SEQ, blk, 0, stream>>>(out, meanp, rstdp);
  bn_apply<<<(NROWS * CH) / 256, blk, 0, stream>>>(out, out, meanp, rstdp, bn2g, bn2b);
}